// Round 10
// baseline (64.357 us; speedup 1.0000x reference)
//
#include <hip/hip_runtime.h>

#define NXD   512
#define NYD   512
#define CD    64
#define BD    4
#define GRIDC (NXD * NYD)          // 262144 cells per frame (NZ==1)

// map encoding: bits[0:16] = row+1 (<=65536), bits[17:22] = npts (<=32), bit23 = selected
#define ROW_MASK   0x1FFFF
#define NPTS_SHIFT 17
#define SEL_FLAG   (1 << 23)

// 1024 cells per logical block (R5 structure), grid-strided over 2048 real blocks
#define CELLS_PER_BLOCK 1024
#define CHUNKS_PER_PLANE (GRIDC / CELLS_PER_BLOCK)           // 256
#define SPATIAL_BLOCKS   (BD * CD * CHUNKS_PER_PLANE)        // 65536
#define META_BLOCKS      (BD * GRIDC / CELLS_PER_BLOCK)      // 1024
#define TOTAL_IDS        (SPATIAL_BLOCKS + META_BLOCKS)      // 66560
#define GRID_BLOCKS      2048                                // 256 CU x 8

typedef float f32x4 __attribute__((ext_vector_type(4)));
typedef int   i32x4 __attribute__((ext_vector_type(4)));

// ---------------- fused path ----------------

// atomicOr so the pillar write and the selected-flag write compose in any order.
// Tail threads [M+K, M+K+64) zero the 256B zero-gather page.
__global__ void build_map_kernel(const int* __restrict__ coords,
                                 const int* __restrict__ sel,
                                 const int* __restrict__ npts,
                                 int* __restrict__ map,
                                 float* __restrict__ zerobuf,
                                 int M, int K) {
    int i = blockIdx.x * blockDim.x + threadIdx.x;
    if (i < M) {
        i32x4 cr = *reinterpret_cast<const i32x4*>(coords + 4 * i);
        int cell = cr.x * GRIDC + cr.y + cr.z * NXD + cr.w;
        atomicOr(map + cell, (i + 1) | (npts[i] << NPTS_SHIFT));
    } else if (i < M + K) {
        int r = sel[i - M];
        i32x4 cr = *reinterpret_cast<const i32x4*>(coords + 4 * r);
        int cell = cr.x * GRIDC + cr.y + cr.z * NXD + cr.w;
        atomicOr(map + cell, SEL_FLAG);
    } else if (i < M + K + CD) {
        zerobuf[i - (M + K)] = 0.0f;
    }
}

// Grid-stride LINEAR-store one-pass fill. Logical id >= META_BLOCKS is a
// spatial unit owning the contiguous 4KB output span [sbid*1024, +1024)
// floats == (frame b, channel c, 1024 cells); thread t handles cells t*4
// (wave-contiguous map loads and NT stores). ids < META_BLOCKS write the
// three meta maps. 2048 persistent blocks x ~32 independent iterations ->
// cross-iteration ILP + 32x fewer workgroup dispatches. In-flight window of
// 2048 ids = 8 channels x 256 chunks; sbid deltas of 256 are 0 mod 8 so
// same-chunk ids stay co-XCD (map slice L2-hot). NT stores keep the map
// L2-resident (R8 A/B: cached stores +6us via map eviction).
__global__ __launch_bounds__(256) void linear_fill_kernel(
        const float* __restrict__ feats,
        const int*   __restrict__ map,
        const float* __restrict__ zerobuf,
        float* __restrict__ out) {
    const int t = threadIdx.x;

    for (int id = blockIdx.x; id < TOTAL_IDS; id += GRID_BLOCKS) {
        if (id >= META_BLOCKS) {
            const int sbid = id - META_BLOCKS;
            // sbid = ((b*64 + c) * 256 + chunk)
            const int b     = sbid >> 14;
            const int c     = (sbid >> 8) & 63;
            const int chunk = sbid & 255;
            const int cell0 = chunk * CELLS_PER_BLOCK + t * 4;    // within frame

            const i32x4 m4 = *reinterpret_cast<const i32x4*>(
                map + (size_t)b * GRIDC + cell0);
            const int rows[4] = {m4.x, m4.y, m4.z, m4.w};

            f32x4 v;
            #pragma unroll
            for (int j = 0; j < 4; ++j) {
                int m = rows[j];
                const float* p = (m & SEL_FLAG)
                    ? (feats + ((size_t)((m & ROW_MASK) - 1) << 6))
                    : zerobuf;
                v[j] = p[c];
            }
            __builtin_nontemporal_store(
                v, reinterpret_cast<f32x4*>(out + (size_t)sbid * CELLS_PER_BLOCK + t * 4));
        } else {
            // meta: occ / dens / pnum, each [B][GRIDC], after the spatial region
            const size_t cbase = (size_t)id * CELLS_PER_BLOCK + t * 4;

            const i32x4 m4 = *reinterpret_cast<const i32x4*>(map + cbase);
            const int rows[4] = {m4.x, m4.y, m4.z, m4.w};

            const size_t spatial_elems = (size_t)BD * CD * GRIDC;
            const size_t map_elems     = (size_t)BD * GRIDC;
            float* __restrict__ occ  = out + spatial_elems;
            float* __restrict__ dens = occ + map_elems;
            float* __restrict__ pnum = dens + map_elems;

            f32x4 o, d, pn;
            #pragma unroll
            for (int j = 0; j < 4; ++j) {
                int m = rows[j];
                if (m != 0) {
                    float n = (float)((m >> NPTS_SHIFT) & 63);
                    o[j] = 1.0f;
                    d[j] = n * (1.0f / 32.0f);
                    pn[j] = n;
                } else {
                    o[j] = 0.f; d[j] = 0.f; pn[j] = 0.f;
                }
            }
            __builtin_nontemporal_store(o,  reinterpret_cast<f32x4*>(occ  + cbase));
            __builtin_nontemporal_store(d,  reinterpret_cast<f32x4*>(dens + cbase));
            __builtin_nontemporal_store(pn, reinterpret_cast<f32x4*>(pnum + cbase));
        }
    }
}

// ---------------- fallback path (used only if ws too small) ----------------

__global__ void scatter_meta_kernel(const int* __restrict__ coords,
                                    const int* __restrict__ npts,
                                    float* __restrict__ occ,
                                    float* __restrict__ dens,
                                    float* __restrict__ pnum,
                                    int M) {
    int i = blockIdx.x * blockDim.x + threadIdx.x;
    if (i >= M) return;
    int b = coords[4 * i + 0];
    int z = coords[4 * i + 1];
    int y = coords[4 * i + 2];
    int x = coords[4 * i + 3];
    int cell = b * GRIDC + z + y * NXD + x;
    float n = (float)npts[i];
    occ[cell]  = 1.0f;
    dens[cell] = n * (1.0f / 32.0f);
    pnum[cell] = n;
}

__global__ void scatter_spatial_kernel(const float* __restrict__ feats,
                                       const int* __restrict__ coords,
                                       const int* __restrict__ sel,
                                       float* __restrict__ spatial,
                                       int K) {
    int group = blockIdx.x * (blockDim.x >> 6) + (threadIdx.x >> 6);
    int c     = threadIdx.x & 63;
    if (group >= K) return;
    int row = sel[group];
    int b = coords[4 * row + 0];
    int z = coords[4 * row + 1];
    int y = coords[4 * row + 2];
    int x = coords[4 * row + 3];
    int cell = z + y * NXD + x;
    float v = feats[(size_t)row * CD + c];
    spatial[(size_t)b * ((size_t)CD * GRIDC) + (size_t)c * GRIDC + (size_t)cell] = v;
}

extern "C" void kernel_launch(void* const* d_in, const int* in_sizes, int n_in,
                              void* d_out, int out_size, void* d_ws, size_t ws_size,
                              hipStream_t stream) {
    const float* feats  = (const float*)d_in[0];  // [M, 64] f32
    const int*   coords = (const int*)d_in[1];    // [M, 4]  (b,z,y,x)
    const int*   npts   = (const int*)d_in[2];    // [M]
    const int*   sel    = (const int*)d_in[3];    // [K]

    const int M = in_sizes[2];
    const int K = in_sizes[3];

    float* out = (float*)d_out;
    const size_t map_bytes  = (size_t)BD * GRIDC * sizeof(int);  // 4 MB
    const size_t zero_bytes = CD * sizeof(float);                // 256 B

    if (ws_size >= map_bytes + zero_bytes) {
        int* map = (int*)d_ws;
        float* zerobuf = (float*)((char*)d_ws + map_bytes);
        (void)hipMemsetAsync(map, 0, map_bytes, stream);
        build_map_kernel<<<(M + K + CD + 255) / 256, 256, 0, stream>>>(
            coords, sel, npts, map, zerobuf, M, K);
        linear_fill_kernel<<<GRID_BLOCKS, 256, 0, stream>>>(
            feats, map, zerobuf, out);
    } else {
        // fallback: memset + scatter
        size_t spatial_elems = (size_t)BD * CD * GRIDC;
        size_t map_elems     = (size_t)BD * GRIDC;
        float* occ  = out + spatial_elems;
        float* dens = occ + map_elems;
        float* pnum = dens + map_elems;
        (void)hipMemsetAsync(d_out, 0, (size_t)out_size * sizeof(float), stream);
        scatter_meta_kernel<<<(M + 255) / 256, 256, 0, stream>>>(
            coords, npts, occ, dens, pnum, M);
        scatter_spatial_kernel<<<(K + 3) / 4, 256, 0, stream>>>(
            feats, coords, sel, out, K);
    }
}

// Round 11
// 61.654 us; speedup vs baseline: 1.0438x; 1.0438x over previous
//
#include <hip/hip_runtime.h>

#define NXD   512
#define NYD   512
#define CD    64
#define BD    4
#define GRIDC (NXD * NYD)          // 262144 cells per frame (NZ==1)

// map encoding: bits[0:16] = row+1 (<=65536), bits[17:22] = npts (<=32), bit23 = selected
#define ROW_MASK   0x1FFFF
#define NPTS_SHIFT 17
#define SEL_FLAG   (1 << 23)

// R5 structure, channel-paired: block = (frame b, channel-pair cp, 1024 cells)
#define CELLS_PER_BLOCK 1024
#define CHUNKS_PER_PLANE (GRIDC / CELLS_PER_BLOCK)           // 256
#define SPATIAL_BLOCKS   (BD * (CD / 2) * CHUNKS_PER_PLANE)  // 32768
#define META_BLOCKS      (BD * GRIDC / CELLS_PER_BLOCK)      // 1024

typedef float f32x4 __attribute__((ext_vector_type(4)));
typedef int   i32x4 __attribute__((ext_vector_type(4)));

// ---------------- fused path ----------------

// atomicOr so the pillar write and the selected-flag write compose in any order.
// Tail threads [M+K, M+K+64) zero the 256B zero-gather page.
__global__ void build_map_kernel(const int* __restrict__ coords,
                                 const int* __restrict__ sel,
                                 const int* __restrict__ npts,
                                 int* __restrict__ map,
                                 float* __restrict__ zerobuf,
                                 int M, int K) {
    int i = blockIdx.x * blockDim.x + threadIdx.x;
    if (i < M) {
        i32x4 cr = *reinterpret_cast<const i32x4*>(coords + 4 * i);
        int cell = cr.x * GRIDC + cr.y + cr.z * NXD + cr.w;
        atomicOr(map + cell, (i + 1) | (npts[i] << NPTS_SHIFT));
    } else if (i < M + K) {
        int r = sel[i - M];
        i32x4 cr = *reinterpret_cast<const i32x4*>(coords + 4 * r);
        int cell = cr.x * GRIDC + cr.y + cr.z * NXD + cr.w;
        atomicOr(map + cell, SEL_FLAG);
    } else if (i < M + K + CD) {
        zerobuf[i - (M + K)] = 0.0f;
    }
}

// R5 linear-store one-pass fill with CHANNEL PAIRING: spatial block sbid =
// ((b*32 + cp) * 256 + chunk) produces channels c0=2cp, c1=2cp+1 for its
// 1024 cells from ONE i32x4 map load per thread (halves total map L2 reads
// vs R5's one-channel blocks; second gather hits the same 64B feats line).
// Each of the two NT store streams is wave-contiguous 4KB. sbid deltas
// between same-chunk blocks are multiples of 256 (0 mod 8) -> co-XCD, map
// slice + feats rows fetched ~once per XCD. NT stores keep the 4MB map
// L2-resident (R8 A/B: cached stores +6us). Meta blocks at grid tail (R5).
__global__ __launch_bounds__(256) void linear_fill_kernel(
        const float* __restrict__ feats,
        const int*   __restrict__ map,
        const float* __restrict__ zerobuf,
        float* __restrict__ out) {
    const int bid = blockIdx.x;
    const int t   = threadIdx.x;

    if (bid < SPATIAL_BLOCKS) {
        // sbid = ((b*32 + cp) * 256 + chunk)
        const int b     = bid >> 13;            // / (32*256)
        const int cp    = (bid >> 8) & 31;
        const int chunk = bid & 255;
        const int c0    = cp * 2;
        const int cell0 = chunk * CELLS_PER_BLOCK + t * 4;    // within frame

        const i32x4 m4 = *reinterpret_cast<const i32x4*>(
            map + (size_t)b * GRIDC + cell0);
        const int rows[4] = {m4.x, m4.y, m4.z, m4.w};

        f32x4 v0, v1;
        #pragma unroll
        for (int j = 0; j < 4; ++j) {
            int m = rows[j];
            const float* p = (m & SEL_FLAG)
                ? (feats + ((size_t)((m & ROW_MASK) - 1) << 6))
                : zerobuf;
            v0[j] = p[c0];
            v1[j] = p[c0 + 1];
        }
        float* dst = out + (size_t)(b * CD + c0) * GRIDC + cell0;
        __builtin_nontemporal_store(v0, reinterpret_cast<f32x4*>(dst));
        __builtin_nontemporal_store(v1, reinterpret_cast<f32x4*>(dst + GRIDC));
    } else {
        // meta: occ / dens / pnum, each [B][GRIDC], after the spatial region
        const int mid = bid - SPATIAL_BLOCKS;                 // 0..1023
        const size_t cbase = (size_t)mid * CELLS_PER_BLOCK + t * 4;

        const i32x4 m4 = *reinterpret_cast<const i32x4*>(map + cbase);
        const int rows[4] = {m4.x, m4.y, m4.z, m4.w};

        const size_t spatial_elems = (size_t)BD * CD * GRIDC;
        const size_t map_elems     = (size_t)BD * GRIDC;
        float* __restrict__ occ  = out + spatial_elems;
        float* __restrict__ dens = occ + map_elems;
        float* __restrict__ pnum = dens + map_elems;

        f32x4 o, d, pn;
        #pragma unroll
        for (int j = 0; j < 4; ++j) {
            int m = rows[j];
            if (m != 0) {
                float n = (float)((m >> NPTS_SHIFT) & 63);
                o[j] = 1.0f;
                d[j] = n * (1.0f / 32.0f);
                pn[j] = n;
            } else {
                o[j] = 0.f; d[j] = 0.f; pn[j] = 0.f;
            }
        }
        __builtin_nontemporal_store(o,  reinterpret_cast<f32x4*>(occ  + cbase));
        __builtin_nontemporal_store(d,  reinterpret_cast<f32x4*>(dens + cbase));
        __builtin_nontemporal_store(pn, reinterpret_cast<f32x4*>(pnum + cbase));
    }
}

// ---------------- fallback path (used only if ws too small) ----------------

__global__ void scatter_meta_kernel(const int* __restrict__ coords,
                                    const int* __restrict__ npts,
                                    float* __restrict__ occ,
                                    float* __restrict__ dens,
                                    float* __restrict__ pnum,
                                    int M) {
    int i = blockIdx.x * blockDim.x + threadIdx.x;
    if (i >= M) return;
    int b = coords[4 * i + 0];
    int z = coords[4 * i + 1];
    int y = coords[4 * i + 2];
    int x = coords[4 * i + 3];
    int cell = b * GRIDC + z + y * NXD + x;
    float n = (float)npts[i];
    occ[cell]  = 1.0f;
    dens[cell] = n * (1.0f / 32.0f);
    pnum[cell] = n;
}

__global__ void scatter_spatial_kernel(const float* __restrict__ feats,
                                       const int* __restrict__ coords,
                                       const int* __restrict__ sel,
                                       float* __restrict__ spatial,
                                       int K) {
    int group = blockIdx.x * (blockDim.x >> 6) + (threadIdx.x >> 6);
    int c     = threadIdx.x & 63;
    if (group >= K) return;
    int row = sel[group];
    int b = coords[4 * row + 0];
    int z = coords[4 * row + 1];
    int y = coords[4 * row + 2];
    int x = coords[4 * row + 3];
    int cell = z + y * NXD + x;
    float v = feats[(size_t)row * CD + c];
    spatial[(size_t)b * ((size_t)CD * GRIDC) + (size_t)c * GRIDC + (size_t)cell] = v;
}

extern "C" void kernel_launch(void* const* d_in, const int* in_sizes, int n_in,
                              void* d_out, int out_size, void* d_ws, size_t ws_size,
                              hipStream_t stream) {
    const float* feats  = (const float*)d_in[0];  // [M, 64] f32
    const int*   coords = (const int*)d_in[1];    // [M, 4]  (b,z,y,x)
    const int*   npts   = (const int*)d_in[2];    // [M]
    const int*   sel    = (const int*)d_in[3];    // [K]

    const int M = in_sizes[2];
    const int K = in_sizes[3];

    float* out = (float*)d_out;
    const size_t map_bytes  = (size_t)BD * GRIDC * sizeof(int);  // 4 MB
    const size_t zero_bytes = CD * sizeof(float);                // 256 B

    if (ws_size >= map_bytes + zero_bytes) {
        int* map = (int*)d_ws;
        float* zerobuf = (float*)((char*)d_ws + map_bytes);
        (void)hipMemsetAsync(map, 0, map_bytes, stream);
        build_map_kernel<<<(M + K + CD + 255) / 256, 256, 0, stream>>>(
            coords, sel, npts, map, zerobuf, M, K);
        linear_fill_kernel<<<SPATIAL_BLOCKS + META_BLOCKS, 256, 0, stream>>>(
            feats, map, zerobuf, out);
    } else {
        // fallback: memset + scatter
        size_t spatial_elems = (size_t)BD * CD * GRIDC;
        size_t map_elems     = (size_t)BD * GRIDC;
        float* occ  = out + spatial_elems;
        float* dens = occ + map_elems;
        float* pnum = dens + map_elems;
        (void)hipMemsetAsync(d_out, 0, (size_t)out_size * sizeof(float), stream);
        scatter_meta_kernel<<<(M + 255) / 256, 256, 0, stream>>>(
            coords, npts, occ, dens, pnum, M);
        scatter_spatial_kernel<<<(K + 3) / 4, 256, 0, stream>>>(
            feats, coords, sel, out, K);
    }
}

// Round 12
// 58.169 us; speedup vs baseline: 1.1064x; 1.0599x over previous
//
#include <hip/hip_runtime.h>

#define NXD   512
#define NYD   512
#define CD    64
#define BD    4
#define GRIDC (NXD * NYD)          // 262144 cells per frame (NZ==1)

// map encoding: bits[0:16] = row+1 (<=65536), bits[17:22] = npts (<=32), bit23 = selected
#define ROW_MASK   0x1FFFF
#define NPTS_SHIFT 17
#define SEL_FLAG   (1 << 23)

#define CHUNKS_PER_PLANE (GRIDC / 1024)                  // 256
#define SPATIAL_BLOCKS   (BD * CD * CHUNKS_PER_PLANE)    // 65536
#define META_BLOCKS      (BD * GRIDC / 1024)             // 1024

typedef float f32x4 __attribute__((ext_vector_type(4)));
typedef int   i32x4 __attribute__((ext_vector_type(4)));

// ---------------- fused path ----------------

// atomicOr so the pillar write and the selected-flag write compose in any order.
__global__ void build_map_kernel(const int* __restrict__ coords,
                                 const int* __restrict__ sel,
                                 const int* __restrict__ npts,
                                 int* __restrict__ map, int M, int K) {
    int i = blockIdx.x * blockDim.x + threadIdx.x;
    if (i < M) {
        int b = coords[4 * i + 0];
        int z = coords[4 * i + 1];
        int y = coords[4 * i + 2];
        int x = coords[4 * i + 3];
        int cell = b * GRIDC + z + y * NXD + x;
        atomicOr(map + cell, (i + 1) | (npts[i] << NPTS_SHIFT));
    } else if (i < M + K) {
        int r = sel[i - M];
        int b = coords[4 * r + 0];
        int z = coords[4 * r + 1];
        int y = coords[4 * r + 2];
        int x = coords[4 * r + 3];
        int cell = b * GRIDC + z + y * NXD + x;
        atomicOr(map + cell, SEL_FLAG);
    }
}

// LINEAR-store one-pass fill: block bid < SPATIAL_BLOCKS owns the 4KB output
// span [bid*1024, bid*1024+1024) floats == (frame b, channel c, 1024 cells).
// Consecutive blocks write consecutive addresses -> fill-like streaming.
// Tail blocks write the three meta maps (3 linear streams).
__global__ __launch_bounds__(256) void linear_fill_kernel(
        const float* __restrict__ feats,
        const int*   __restrict__ map,
        const float* __restrict__ zerobuf,
        float* __restrict__ out) {
    const int bid = blockIdx.x;
    const int t   = threadIdx.x;

    if (bid < SPATIAL_BLOCKS) {
        // bid = ((b*64 + c) * 256 + chunk)
        const int b     = bid >> 14;            // / (64*256)
        const int c     = (bid >> 8) & 63;
        const int chunk = bid & 255;
        const int cell0 = chunk * 1024 + t * 4; // cell within frame

        const i32x4 m4 = *reinterpret_cast<const i32x4*>(
            map + (size_t)b * GRIDC + cell0);
        const int rows[4] = {m4.x, m4.y, m4.z, m4.w};

        f32x4 v;
        #pragma unroll
        for (int j = 0; j < 4; ++j) {
            int m = rows[j];
            // branch-free: unselected cells read zerobuf[c] (L1 broadcast)
            const float* p = (m & SEL_FLAG)
                ? (feats + ((size_t)((m & ROW_MASK) - 1) << 6))
                : zerobuf;
            v[j] = p[c];
        }
        __builtin_nontemporal_store(
            v, reinterpret_cast<f32x4*>(out + (size_t)bid * 1024 + t * 4));
    } else {
        // meta: occ / dens / pnum, each [B][GRIDC], after the spatial region
        const int mid = bid - SPATIAL_BLOCKS;           // 0..1023
        const size_t cbase = (size_t)mid * 1024 + t * 4; // global cell id

        const i32x4 m4 = *reinterpret_cast<const i32x4*>(map + cbase);
        const int rows[4] = {m4.x, m4.y, m4.z, m4.w};

        const size_t spatial_elems = (size_t)BD * CD * GRIDC;
        const size_t map_elems     = (size_t)BD * GRIDC;
        float* __restrict__ occ  = out + spatial_elems;
        float* __restrict__ dens = occ + map_elems;
        float* __restrict__ pnum = dens + map_elems;

        f32x4 o, d, pn;
        #pragma unroll
        for (int j = 0; j < 4; ++j) {
            int m = rows[j];
            if (m != 0) {
                float n = (float)((m >> NPTS_SHIFT) & 63);
                o[j] = 1.0f;
                d[j] = n * (1.0f / 32.0f);
                pn[j] = n;
            } else {
                o[j] = 0.f; d[j] = 0.f; pn[j] = 0.f;
            }
        }
        __builtin_nontemporal_store(o,  reinterpret_cast<f32x4*>(occ  + cbase));
        __builtin_nontemporal_store(d,  reinterpret_cast<f32x4*>(dens + cbase));
        __builtin_nontemporal_store(pn, reinterpret_cast<f32x4*>(pnum + cbase));
    }
}

// ---------------- fallback path (used only if ws too small) ----------------

__global__ void scatter_meta_kernel(const int* __restrict__ coords,
                                    const int* __restrict__ npts,
                                    float* __restrict__ occ,
                                    float* __restrict__ dens,
                                    float* __restrict__ pnum,
                                    int M) {
    int i = blockIdx.x * blockDim.x + threadIdx.x;
    if (i >= M) return;
    int b = coords[4 * i + 0];
    int z = coords[4 * i + 1];
    int y = coords[4 * i + 2];
    int x = coords[4 * i + 3];
    int cell = b * GRIDC + z + y * NXD + x;
    float n = (float)npts[i];
    occ[cell]  = 1.0f;
    dens[cell] = n * (1.0f / 32.0f);
    pnum[cell] = n;
}

__global__ void scatter_spatial_kernel(const float* __restrict__ feats,
                                       const int* __restrict__ coords,
                                       const int* __restrict__ sel,
                                       float* __restrict__ spatial,
                                       int K) {
    int group = blockIdx.x * (blockDim.x >> 6) + (threadIdx.x >> 6);
    int c     = threadIdx.x & 63;
    if (group >= K) return;
    int row = sel[group];
    int b = coords[4 * row + 0];
    int z = coords[4 * row + 1];
    int y = coords[4 * row + 2];
    int x = coords[4 * row + 3];
    int cell = z + y * NXD + x;
    float v = feats[(size_t)row * CD + c];
    spatial[(size_t)b * ((size_t)CD * GRIDC) + (size_t)c * GRIDC + (size_t)cell] = v;
}

extern "C" void kernel_launch(void* const* d_in, const int* in_sizes, int n_in,
                              void* d_out, int out_size, void* d_ws, size_t ws_size,
                              hipStream_t stream) {
    const float* feats  = (const float*)d_in[0];  // [M, 64] f32
    const int*   coords = (const int*)d_in[1];    // [M, 4]  (b,z,y,x)
    const int*   npts   = (const int*)d_in[2];    // [M]
    const int*   sel    = (const int*)d_in[3];    // [K]

    const int M = in_sizes[2];
    const int K = in_sizes[3];

    float* out = (float*)d_out;
    const size_t map_bytes  = (size_t)BD * GRIDC * sizeof(int);  // 4 MB
    const size_t zero_bytes = CD * sizeof(float);                // 256 B

    if (ws_size >= map_bytes + zero_bytes) {
        int* map = (int*)d_ws;
        const float* zerobuf = (const float*)((char*)d_ws + map_bytes);
        (void)hipMemsetAsync(d_ws, 0, map_bytes + zero_bytes, stream);
        build_map_kernel<<<(M + K + 255) / 256, 256, 0, stream>>>(
            coords, sel, npts, map, M, K);
        linear_fill_kernel<<<SPATIAL_BLOCKS + META_BLOCKS, 256, 0, stream>>>(
            feats, map, zerobuf, out);
    } else {
        // fallback: memset + scatter
        size_t spatial_elems = (size_t)BD * CD * GRIDC;
        size_t map_elems     = (size_t)BD * GRIDC;
        float* occ  = out + spatial_elems;
        float* dens = occ + map_elems;
        float* pnum = dens + map_elems;
        (void)hipMemsetAsync(d_out, 0, (size_t)out_size * sizeof(float), stream);
        scatter_meta_kernel<<<(M + 255) / 256, 256, 0, stream>>>(
            coords, npts, occ, dens, pnum, M);
        scatter_spatial_kernel<<<(K + 3) / 4, 256, 0, stream>>>(
            feats, coords, sel, out, K);
    }
}